// Round 6
// baseline (195.473 us; speedup 1.0000x reference)
//
#include <hip/hip_runtime.h>
#include <stdint.h>

// Input  x[b,t,h,w,c] : (4, 200, 64, 64, 8) fp32, n = h*512 + wc (wc = w*8+c)
// Output out[b,t,w,c,h]: (4, 200, 64, 8, 64) fp32
// Per neuron, per 100-step chunk: acc += x[t]; if (acc > 2) { spike=1; acc=0; }
//
// K1 spike_bits_async (UNCHANGED control, round-5): async global->LDS scan,
//    counted vmcnt window of 20 planes, wave-private slots, bit-packed output.
// K2 expand_bits2 (NEW experiment): write-chunk enlargement. Block = (slab,
//    wc-tile of 64, t-group of 12/13). Per t: 16 KB contiguous store burst
//    (vs 8 KB before). Bit-planes staged once to LDS (33 KB), expansion from
//    16 hoisted registers. Tests whether the ~3 TB/s strided-stream rate is
//    chunk-size-limited (row locality) or invariant.
#define HWC    32768
#define NSLAB  8
#define TTOT   200
#define CHUNK  100

// ---------------- K1: async bit-packed integrate-and-fire scan -------------
__global__ __launch_bounds__(256) void spike_bits_async(const float* __restrict__ x,
                                                        uint32_t* __restrict__ spk) {
    __shared__ float lds[20 * 256];                    // 20 slots x 4 waves x 64

    unsigned g    = blockIdx.x * 256u + threadIdx.x;   // [0, 262144)
    unsigned slab = g >> 15;                           // [0, 8)
    unsigned n    = g & 32767u;
    unsigned b    = slab >> 1, ch = slab & 1u;
    const float* xb = x + (size_t)(b * TTOT + ch * CHUNK) * HWC + n;

    unsigned lane = threadIdx.x & 63u;
    float*   lw   = &lds[(threadIdx.x >> 6) * 64u];    // wave-uniform base

    float acc = 0.0f;
    uint32_t w[4] = {0u, 0u, 0u, 0u};

#define GL(T, SLOT)                                                        \
    __builtin_amdgcn_global_load_lds(                                      \
        (const __attribute__((address_space(1))) void*)(xb + (size_t)(T) * HWC), \
        (__attribute__((address_space(3))) void*)(lw + (SLOT) * 256u),     \
        4, 0, 0)

#define STC(T, SLOT, VN)                                                   \
    do {                                                                   \
        asm volatile("s_waitcnt vmcnt(" #VN ")" ::: "memory");             \
        __builtin_amdgcn_sched_barrier(0);                                 \
        float v = lw[(SLOT) * 256u + lane];                                \
        acc += v;                                                          \
        if (acc > 2.0f) { w[(T) >> 5] |= (1u << ((T) & 31)); acc = 0.0f; } \
    } while (0)

#define ST(T, SLOT) do { STC(T, SLOT, 19); GL((T) + 20, SLOT); } while (0)
#define ROW5(T0, S0) ST(T0, S0); ST((T0)+1, (S0)+1); ST((T0)+2, (S0)+2); \
                     ST((T0)+3, (S0)+3); ST((T0)+4, (S0)+4)
#define ROW20(T0) ROW5(T0, 0); ROW5((T0)+5, 5); ROW5((T0)+10, 10); ROW5((T0)+15, 15)

#pragma unroll
    for (int t = 0; t < 20; ++t) GL(t, t);

    ROW20(0); ROW20(20); ROW20(40); ROW20(60);

    STC(80,  0, 19); STC(81,  1, 18); STC(82,  2, 17); STC(83,  3, 16);
    STC(84,  4, 15); STC(85,  5, 14); STC(86,  6, 13); STC(87,  7, 12);
    STC(88,  8, 11); STC(89,  9, 10); STC(90, 10,  9); STC(91, 11,  8);
    STC(92, 12,  7); STC(93, 13,  6); STC(94, 14,  5); STC(95, 15,  4);
    STC(96, 16,  3); STC(97, 17,  2); STC(98, 18,  1); STC(99, 19,  0);

#undef ROW20
#undef ROW5
#undef ST
#undef STC
#undef GL

    uint32_t* sp = spk + ((size_t)slab << 17) + n;     // [slab][tw][n]
    sp[0]            = w[0];
    sp[HWC]          = w[1];
    sp[2u * HWC]     = w[2];
    sp[3u * HWC]     = w[3];
}

// ---------------- K2: bit expand + transpose, 16 KB write bursts -----------
// 512 blocks x 512 threads. Block = (slab, wcTile of 64, tGroup of 12/13).
// LDS: 2 bit-planes x [64 h][64 wc pad 65] = 33.3 KB -> 2 blocks/CU.
__global__ __launch_bounds__(512) void expand_bits2(const uint32_t* __restrict__ spk,
                                                    float* __restrict__ out) {
    __shared__ uint32_t lds[2 * 4160];           // 2 x 64*65

    static const unsigned char tstart[8] = {0, 13, 25, 38, 50, 63, 75, 88};
    static const unsigned char tlen[8]   = {13, 12, 13, 12, 13, 12, 13, 12};

    unsigned gid  = blockIdx.x;                  // [0, 512)
    unsigned slab = gid >> 6;                    // [0, 8)
    unsigned wcT  = (gid >> 3) & 7u;             // [0, 8)
    unsigned grp  = gid & 7u;                    // [0, 8)
    unsigned wc0  = wcT * 64u;
    unsigned t0   = tstart[grp];
    unsigned L    = tlen[grp];
    unsigned p0   = t0 >> 5;                     // first bit-plane touched
    unsigned p1   = (t0 + L - 1u) >> 5;          // second (may equal p0)
    unsigned tid  = threadIdx.x;

    // ---- stage 2 bit-planes (wc-tile x all h) into LDS ----
    const uint32_t* sbase = spk + ((size_t)slab << 17);
#pragma unroll
    for (int p = 0; p < 2; ++p) {
        unsigned tw = p ? p1 : p0;
#pragma unroll
        for (int it = 0; it < 8; ++it) {
            unsigned idx = it * 512u + tid;      // [0, 4096)
            unsigned h   = idx >> 6, wcl = idx & 63u;
            lds[p * 4160u + h * 65u + wcl] =
                sbase[((size_t)tw << 15) + h * 512u + wc0 + wcl];
        }
    }
    __syncthreads();

    // ---- hoist this thread's 16 bit-words to registers ----
    // thread covers float4 slots f = j*512 + tid (j=0,1):
    //   wcl = f>>4 in [0,64), h0 = (f&15)*4
    unsigned h0   = (tid & 15u) * 4u;
    unsigned wclA = tid >> 4;                    // j = 0
    unsigned wclB = 32u + (tid >> 4);            // j = 1
    uint32_t r0[2][4], r1[2][4];                 // [j][k], plane 0 / plane 1
#pragma unroll
    for (int k = 0; k < 4; ++k) {
        r0[0][k] = lds[(h0 + k) * 65u + wclA];
        r0[1][k] = lds[(h0 + k) * 65u + wclB];
        r1[0][k] = lds[4160u + (h0 + k) * 65u + wclA];
        r1[1][k] = lds[4160u + (h0 + k) * 65u + wclB];
    }

    unsigned b = slab >> 1, ch = slab & 1u;
    unsigned rbase = b * TTOT + ch * CHUNK;
    float4* o4 = (float4*)out;

    // ---- t-loop: per t, 16 KB contiguous burst (1024 float4 by 512 thr) ----
    for (unsigned j = 0; j < L; ++j) {
        unsigned t   = t0 + j;
        unsigned sel = (t >> 5) != p0;           // wave-uniform
        unsigned bit = t & 31u;
        size_t   pb  = ((size_t)(rbase + t) << 13) + (size_t)wc0 * 16u;

        uint32_t a0 = sel ? r1[0][0] : r0[0][0];
        uint32_t a1 = sel ? r1[0][1] : r0[0][1];
        uint32_t a2 = sel ? r1[0][2] : r0[0][2];
        uint32_t a3 = sel ? r1[0][3] : r0[0][3];
        float4 v;
        v.x = (float)((a0 >> bit) & 1u);
        v.y = (float)((a1 >> bit) & 1u);
        v.z = (float)((a2 >> bit) & 1u);
        v.w = (float)((a3 >> bit) & 1u);
        o4[pb + tid] = v;

        uint32_t c0 = sel ? r1[1][0] : r0[1][0];
        uint32_t c1 = sel ? r1[1][1] : r0[1][1];
        uint32_t c2 = sel ? r1[1][2] : r0[1][2];
        uint32_t c3 = sel ? r1[1][3] : r0[1][3];
        float4 u;
        u.x = (float)((c0 >> bit) & 1u);
        u.y = (float)((c1 >> bit) & 1u);
        u.z = (float)((c2 >> bit) & 1u);
        u.w = (float)((c3 >> bit) & 1u);
        o4[pb + 512u + tid] = u;
    }
}

// ---------------- Fallback (ws too small): in-place scheme -----------------
__global__ __launch_bounds__(256) void spike_kernel_ip(const float* __restrict__ x,
                                                       uint8_t* __restrict__ spk) {
    unsigned g     = blockIdx.x * 256u + threadIdx.x;
    unsigned chunk = g >> 16;
    unsigned p     = g & 65535u;
    unsigned b     = p >> 14;
    unsigned i     = (p & 16383u) * 2u;
    unsigned t0    = b * TTOT + chunk * CHUNK;
    const float2* xp = (const float2*)(x + (size_t)t0 * HWC + i);
    uint8_t*      sp = spk + (size_t)t0 * 131072u + i;
    float a0 = 0.0f, a1 = 0.0f;
    for (int tb = 0; tb < CHUNK; tb += 4) {
        float2 v[4];
#pragma unroll
        for (int k = 0; k < 4; ++k) v[k] = xp[(size_t)k * (HWC / 2)];
        xp += 4 * (HWC / 2);
#pragma unroll
        for (int k = 0; k < 4; ++k) {
            a0 += v[k].x; a1 += v[k].y;
            unsigned s0 = 0u, s1 = 0u;
            if (a0 > 2.0f) { s0 = 1u; a0 = 0.0f; }
            if (a1 > 2.0f) { s1 = 1u; a1 = 0.0f; }
            *(uint16_t*)sp = (uint16_t)(s0 | (s1 << 8));
            sp += 131072u;
        }
    }
}

__global__ __launch_bounds__(512) void transpose_ip(float* __restrict__ out) {
    __shared__ uint32_t lds[64 * 129];
    unsigned region = blockIdx.x;
    unsigned tid = threadIdx.x;
    const uint32_t* in32 = (const uint32_t*)((const uint8_t*)out + (size_t)region * 131072u);
#pragma unroll
    for (int it = 0; it < 16; ++it) {
        unsigned idx = it * 512u + tid;
        unsigned h = idx >> 7, wq = idx & 127u;
        lds[h * 129u + wq] = in32[idx];
    }
    __syncthreads();
    float4* out4 = (float4*)out + (size_t)region * 8192u;
#pragma unroll
    for (int it = 0; it < 16; ++it) {
        unsigned f  = it * 512u + tid;
        unsigned wc = f >> 4;
        unsigned h0 = (f & 15u) << 2;
        unsigned wq = wc >> 2, sel = (wc & 3u) * 8u;
        float4 v;
        v.x = (float)((lds[(h0 + 0u) * 129u + wq] >> sel) & 1u);
        v.y = (float)((lds[(h0 + 1u) * 129u + wq] >> sel) & 1u);
        v.z = (float)((lds[(h0 + 2u) * 129u + wq] >> sel) & 1u);
        v.w = (float)((lds[(h0 + 3u) * 129u + wq] >> sel) & 1u);
        out4[f] = v;
    }
}

extern "C" void kernel_launch(void* const* d_in, const int* in_sizes, int n_in,
                              void* d_out, int out_size, void* d_ws, size_t ws_size,
                              hipStream_t stream) {
    (void)in_sizes; (void)n_in; (void)out_size;
    const float* x = (const float*)d_in[0];
    float* out = (float*)d_out;

    const size_t bit_bytes = (size_t)NSLAB * 4u * HWC * 4u;   // 4 MB
    if (ws_size >= bit_bytes) {
        uint32_t* spk = (uint32_t*)d_ws;
        hipLaunchKernelGGL(spike_bits_async, dim3(1024), dim3(256), 0, stream, x, spk);
        hipLaunchKernelGGL(expand_bits2, dim3(512), dim3(512), 0, stream, spk, out);
    } else {
        hipLaunchKernelGGL(spike_kernel_ip, dim3(512), dim3(256), 0, stream, x, (uint8_t*)out);
        hipLaunchKernelGGL(transpose_ip, dim3(NSLAB * CHUNK), dim3(512), 0, stream, out);
    }
}

// Round 7
// 194.906 us; speedup vs baseline: 1.0029x; 1.0029x over previous
//
#include <hip/hip_runtime.h>
#include <stdint.h>

// MEASUREMENT ROUND: byte-identical round-3 pipeline (best: 181.3 us), but
// expand_bits is launched TWICE (idempotent: same bits -> same output).
// dur_us - 181.3 = K2's duration, pinning the K1/K2 split inside the 58.5 us
// of non-fill time that has been invariant across 4 different K1 structures.
#define HWC    32768
#define NSLAB  8
#define TTOT   200
#define CHUNK  100

// ---------------- K1: bit-packed integrate-and-fire scan (float4) ----------
__global__ __launch_bounds__(256) void spike_bits4(const float* __restrict__ x,
                                                   uint32_t* __restrict__ spk) {
    unsigned g    = blockIdx.x * 256u + threadIdx.x;   // [0, 65536)
    unsigned slab = g >> 13;                           // [0, 8)
    unsigned n0   = (g & 8191u) * 4u;                  // 4 consecutive neurons
    unsigned b    = slab >> 1, ch = slab & 1u;
    const float4* xp = (const float4*)(x + (size_t)(b * TTOT + ch * CHUNK) * HWC + n0);

    float a0 = 0.0f, a1 = 0.0f, a2 = 0.0f, a3 = 0.0f;
    uint32_t w[4][4] = {{0u,0u,0u,0u},{0u,0u,0u,0u},{0u,0u,0u,0u},{0u,0u,0u,0u}};
    float4 A[4], B[4];

#define LOAD4(V, TBASE)                                                     \
    do {                                                                    \
        _Pragma("unroll")                                                   \
        for (int k = 0; k < 4; ++k)                                         \
            V[k] = xp[(size_t)((TBASE) + k) * (HWC / 4)];                   \
    } while (0)

#define CONS4(V, TBASE)                                                     \
    do {                                                                    \
        _Pragma("unroll")                                                   \
        for (int k = 0; k < 4; ++k) {                                       \
            const int tw = (TBASE) >> 5, bb = ((TBASE) & 31) + k;           \
            a0 += V[k].x; if (a0 > 2.0f) { w[tw][0] |= (1u << bb); a0 = 0.0f; } \
            a1 += V[k].y; if (a1 > 2.0f) { w[tw][1] |= (1u << bb); a1 = 0.0f; } \
            a2 += V[k].z; if (a2 > 2.0f) { w[tw][2] |= (1u << bb); a2 = 0.0f; } \
            a3 += V[k].w; if (a3 > 2.0f) { w[tw][3] |= (1u << bb); a3 = 0.0f; } \
        }                                                                   \
    } while (0)

    LOAD4(A, 0);  LOAD4(B, 4);
    CONS4(A, 0);  LOAD4(A, 8);
    CONS4(B, 4);  LOAD4(B, 12);
    CONS4(A, 8);  LOAD4(A, 16);
    CONS4(B, 12); LOAD4(B, 20);
    CONS4(A, 16); LOAD4(A, 24);
    CONS4(B, 20); LOAD4(B, 28);
    CONS4(A, 24); LOAD4(A, 32);
    CONS4(B, 28); LOAD4(B, 36);
    CONS4(A, 32); LOAD4(A, 40);
    CONS4(B, 36); LOAD4(B, 44);
    CONS4(A, 40); LOAD4(A, 48);
    CONS4(B, 44); LOAD4(B, 52);
    CONS4(A, 48); LOAD4(A, 56);
    CONS4(B, 52); LOAD4(B, 60);
    CONS4(A, 56); LOAD4(A, 64);
    CONS4(B, 60); LOAD4(B, 68);
    CONS4(A, 64); LOAD4(A, 72);
    CONS4(B, 68); LOAD4(B, 76);
    CONS4(A, 72); LOAD4(A, 80);
    CONS4(B, 76); LOAD4(B, 84);
    CONS4(A, 80); LOAD4(A, 88);
    CONS4(B, 84); LOAD4(B, 92);
    CONS4(A, 88); LOAD4(A, 96);
    CONS4(B, 92);
    CONS4(A, 96);                       // t=96..99 -> word 3, bits 0..3
#undef LOAD4
#undef CONS4

    uint32_t* sp = spk + ((size_t)slab << 17);   // slab stride = 4*HWC u32
#pragma unroll
    for (int tw = 0; tw < 4; ++tw) {
        uint4 o; o.x = w[tw][0]; o.y = w[tw][1]; o.z = w[tw][2]; o.w = w[tw][3];
        *(uint4*)(sp + (size_t)tw * HWC + n0) = o;
    }
}

// ---------------- K2: bit expand + transpose (proven round-0 kernel) -------
__global__ __launch_bounds__(512) void expand_bits(const uint32_t* __restrict__ spk,
                                                   float* __restrict__ out) {
    __shared__ uint32_t lds[2 * 2112];           // 2 planes x 64h x 33 (pad)
    unsigned gid  = blockIdx.x;                  // [0, 512)
    unsigned slab = gid >> 6;
    unsigned q    = (gid >> 4) & 3u;
    unsigned tile = gid & 15u;
    unsigned wc0  = tile * 32u;
    unsigned t0   = q * 25u;
    unsigned p0   = t0 >> 5;                     // first bit-plane (0,0,1,2)
    unsigned p1   = (t0 + 24u) >> 5;             // second bit-plane (0,1,2,3)
    unsigned tid  = threadIdx.x;

    const uint32_t* sbase = spk + ((size_t)slab << 17);
#pragma unroll
    for (int it = 0; it < 8; ++it) {
        unsigned idx = it * 512u + tid;          // [0, 4096)
        unsigned pl  = idx >> 11;                // 0 / 1
        unsigned r   = idx & 2047u;
        unsigned h   = r >> 5, wcl = r & 31u;
        unsigned tw  = pl ? p1 : p0;
        lds[pl * 2112u + h * 33u + wcl] =
            sbase[((size_t)tw << 15) + h * 512u + wc0 + wcl];
    }
    __syncthreads();

    unsigned wcl = tid >> 4;                     // [0, 32)
    unsigned h0  = (tid & 15u) * 4u;             // 0,4,...,60
    uint32_t r0[4], r1[4];
#pragma unroll
    for (int k = 0; k < 4; ++k) {                // 2-way bank aliasing (free)
        r0[k] = lds[(h0 + k) * 33u + wcl];
        r1[k] = lds[2112u + (h0 + k) * 33u + wcl];
    }

    unsigned b = slab >> 1, ch = slab & 1u;
    unsigned rbase = b * TTOT + ch * CHUNK;      // output region index base
    float4* o4 = (float4*)out;

#pragma unroll
    for (int j = 0; j < 25; ++j) {
        unsigned t   = t0 + j;
        unsigned sel = (t >> 5) != p0;           // wave-uniform
        unsigned bit = t & 31u;
        uint32_t a0 = sel ? r1[0] : r0[0];
        uint32_t a1 = sel ? r1[1] : r0[1];
        uint32_t a2 = sel ? r1[2] : r0[2];
        uint32_t a3 = sel ? r1[3] : r0[3];
        float4 v;
        v.x = (float)((a0 >> bit) & 1u);
        v.y = (float)((a1 >> bit) & 1u);
        v.z = (float)((a2 >> bit) & 1u);
        v.w = (float)((a3 >> bit) & 1u);
        o4[(size_t)(rbase + t) * 8192u + wc0 * 16u + tid] = v;
    }
}

// ---------------- Fallback (ws too small): in-place scheme -----------------
__global__ __launch_bounds__(256) void spike_kernel_ip(const float* __restrict__ x,
                                                       uint8_t* __restrict__ spk) {
    unsigned g     = blockIdx.x * 256u + threadIdx.x;
    unsigned chunk = g >> 16;
    unsigned p     = g & 65535u;
    unsigned b     = p >> 14;
    unsigned i     = (p & 16383u) * 2u;
    unsigned t0    = b * TTOT + chunk * CHUNK;
    const float2* xp = (const float2*)(x + (size_t)t0 * HWC + i);
    uint8_t*      sp = spk + (size_t)t0 * 131072u + i;
    float a0 = 0.0f, a1 = 0.0f;
    for (int tb = 0; tb < CHUNK; tb += 4) {
        float2 v[4];
#pragma unroll
        for (int k = 0; k < 4; ++k) v[k] = xp[(size_t)k * (HWC / 2)];
        xp += 4 * (HWC / 2);
#pragma unroll
        for (int k = 0; k < 4; ++k) {
            a0 += v[k].x; a1 += v[k].y;
            unsigned s0 = 0u, s1 = 0u;
            if (a0 > 2.0f) { s0 = 1u; a0 = 0.0f; }
            if (a1 > 2.0f) { s1 = 1u; a1 = 0.0f; }
            *(uint16_t*)sp = (uint16_t)(s0 | (s1 << 8));
            sp += 131072u;
        }
    }
}

__global__ __launch_bounds__(512) void transpose_ip(float* __restrict__ out) {
    __shared__ uint32_t lds[64 * 129];
    unsigned region = blockIdx.x;
    unsigned tid = threadIdx.x;
    const uint32_t* in32 = (const uint32_t*)((const uint8_t*)out + (size_t)region * 131072u);
#pragma unroll
    for (int it = 0; it < 16; ++it) {
        unsigned idx = it * 512u + tid;
        unsigned h = idx >> 7, wq = idx & 127u;
        lds[h * 129u + wq] = in32[idx];
    }
    __syncthreads();
    float4* out4 = (float4*)out + (size_t)region * 8192u;
#pragma unroll
    for (int it = 0; it < 16; ++it) {
        unsigned f  = it * 512u + tid;
        unsigned wc = f >> 4;
        unsigned h0 = (f & 15u) << 2;
        unsigned wq = wc >> 2, sel = (wc & 3u) * 8u;
        float4 v;
        v.x = (float)((lds[(h0 + 0u) * 129u + wq] >> sel) & 1u);
        v.y = (float)((lds[(h0 + 1u) * 129u + wq] >> sel) & 1u);
        v.z = (float)((lds[(h0 + 2u) * 129u + wq] >> sel) & 1u);
        v.w = (float)((lds[(h0 + 3u) * 129u + wq] >> sel) & 1u);
        out4[f] = v;
    }
}

extern "C" void kernel_launch(void* const* d_in, const int* in_sizes, int n_in,
                              void* d_out, int out_size, void* d_ws, size_t ws_size,
                              hipStream_t stream) {
    (void)in_sizes; (void)n_in; (void)out_size;
    const float* x = (const float*)d_in[0];
    float* out = (float*)d_out;

    const size_t bit_bytes = (size_t)NSLAB * 4u * HWC * 4u;   // 4 MB
    if (ws_size >= bit_bytes) {
        uint32_t* spk = (uint32_t*)d_ws;
        hipLaunchKernelGGL(spike_bits4, dim3(256), dim3(256), 0, stream, x, spk);
        hipLaunchKernelGGL(expand_bits, dim3(512), dim3(512), 0, stream, spk, out);
        // duplicate launch (idempotent) -> dur_us - 181.3 == K2's duration
        hipLaunchKernelGGL(expand_bits, dim3(512), dim3(512), 0, stream, spk, out);
    } else {
        hipLaunchKernelGGL(spike_kernel_ip, dim3(512), dim3(256), 0, stream, x, (uint8_t*)out);
        hipLaunchKernelGGL(transpose_ip, dim3(NSLAB * CHUNK), dim3(512), 0, stream, out);
    }
}

// Round 8
// 194.550 us; speedup vs baseline: 1.0047x; 1.0018x over previous
//
#include <hip/hip_runtime.h>
#include <stdint.h>

// Input  x[b,t,h,w,c] : (4, 200, 64, 64, 8) fp32   (105 MB)
// Output out[b,t,w,c,h]: (4, 200, 64, 8, 64) fp32  (105 MB)
// Per neuron, per 100-step chunk: acc += x[t]; if (acc > 2) { spike=1; acc=0; }
//
// Three-kernel pipeline:
//  K0 warm_l3: sequential grid-stride sweep of x -> installs all 105 MB in the
//     256 MB Infinity Cache at full row-buffer efficiency (~6.5 TB/s). Fixes
//     the measured 2.5 TB/s strided-read wall (DRAM row-activation bound:
//     K1's 4 KB-per-128 KB-stride demand stream gives each HBM channel only a
//     fraction of a row per activation; sequential sweep gives full rows).
//  K1 spike_bits4: round-3 scan, now served by L3 hits (no DRAM rows in SRAM).
//  K2 expand_bits: round-0 write-optimal expansion (measured ~14 us, fine).
#define HWC    32768
#define NSLAB  8
#define TTOT   200
#define CHUNK  100

// ---------------- K0: sequential L3-warm sweep -----------------------------
__global__ __launch_bounds__(256) void warm_l3(const float4* __restrict__ x4) {
    float s = 0.0f;
    for (unsigned i = blockIdx.x * 256u + threadIdx.x; i < 6553600u; i += 524288u) {
        float4 v = x4[i];
        s += v.x + v.y + v.z + v.w;
    }
    asm volatile("" :: "v"(s));    // keep loads live (rule 17), no store
}

// ---------------- K1: bit-packed integrate-and-fire scan (float4) ----------
__global__ __launch_bounds__(256) void spike_bits4(const float* __restrict__ x,
                                                   uint32_t* __restrict__ spk) {
    unsigned g    = blockIdx.x * 256u + threadIdx.x;   // [0, 65536)
    unsigned slab = g >> 13;                           // [0, 8)
    unsigned n0   = (g & 8191u) * 4u;                  // 4 consecutive neurons
    unsigned b    = slab >> 1, ch = slab & 1u;
    const float4* xp = (const float4*)(x + (size_t)(b * TTOT + ch * CHUNK) * HWC + n0);

    float a0 = 0.0f, a1 = 0.0f, a2 = 0.0f, a3 = 0.0f;
    uint32_t w[4][4] = {{0u,0u,0u,0u},{0u,0u,0u,0u},{0u,0u,0u,0u},{0u,0u,0u,0u}};
    float4 A[4], B[4];

#define LOAD4(V, TBASE)                                                     \
    do {                                                                    \
        _Pragma("unroll")                                                   \
        for (int k = 0; k < 4; ++k)                                         \
            V[k] = xp[(size_t)((TBASE) + k) * (HWC / 4)];                   \
    } while (0)

#define CONS4(V, TBASE)                                                     \
    do {                                                                    \
        _Pragma("unroll")                                                   \
        for (int k = 0; k < 4; ++k) {                                       \
            const int tw = (TBASE) >> 5, bb = ((TBASE) & 31) + k;           \
            a0 += V[k].x; if (a0 > 2.0f) { w[tw][0] |= (1u << bb); a0 = 0.0f; } \
            a1 += V[k].y; if (a1 > 2.0f) { w[tw][1] |= (1u << bb); a1 = 0.0f; } \
            a2 += V[k].z; if (a2 > 2.0f) { w[tw][2] |= (1u << bb); a2 = 0.0f; } \
            a3 += V[k].w; if (a3 > 2.0f) { w[tw][3] |= (1u << bb); a3 = 0.0f; } \
        }                                                                   \
    } while (0)

    LOAD4(A, 0);  LOAD4(B, 4);
    CONS4(A, 0);  LOAD4(A, 8);
    CONS4(B, 4);  LOAD4(B, 12);
    CONS4(A, 8);  LOAD4(A, 16);
    CONS4(B, 12); LOAD4(B, 20);
    CONS4(A, 16); LOAD4(A, 24);
    CONS4(B, 20); LOAD4(B, 28);
    CONS4(A, 24); LOAD4(A, 32);
    CONS4(B, 28); LOAD4(B, 36);
    CONS4(A, 32); LOAD4(A, 40);
    CONS4(B, 36); LOAD4(B, 44);
    CONS4(A, 40); LOAD4(A, 48);
    CONS4(B, 44); LOAD4(B, 52);
    CONS4(A, 48); LOAD4(A, 56);
    CONS4(B, 52); LOAD4(B, 60);
    CONS4(A, 56); LOAD4(A, 64);
    CONS4(B, 60); LOAD4(B, 68);
    CONS4(A, 64); LOAD4(A, 72);
    CONS4(B, 68); LOAD4(B, 76);
    CONS4(A, 72); LOAD4(A, 80);
    CONS4(B, 76); LOAD4(B, 84);
    CONS4(A, 80); LOAD4(A, 88);
    CONS4(B, 84); LOAD4(B, 92);
    CONS4(A, 88); LOAD4(A, 96);
    CONS4(B, 92);
    CONS4(A, 96);                       // t=96..99 -> word 3, bits 0..3
#undef LOAD4
#undef CONS4

    uint32_t* sp = spk + ((size_t)slab << 17);   // slab stride = 4*HWC u32
#pragma unroll
    for (int tw = 0; tw < 4; ++tw) {
        uint4 o; o.x = w[tw][0]; o.y = w[tw][1]; o.z = w[tw][2]; o.w = w[tw][3];
        *(uint4*)(sp + (size_t)tw * HWC + n0) = o;
    }
}

// ---------------- K2: bit expand + transpose (proven round-0 kernel) -------
__global__ __launch_bounds__(512) void expand_bits(const uint32_t* __restrict__ spk,
                                                   float* __restrict__ out) {
    __shared__ uint32_t lds[2 * 2112];           // 2 planes x 64h x 33 (pad)
    unsigned gid  = blockIdx.x;                  // [0, 512)
    unsigned slab = gid >> 6;
    unsigned q    = (gid >> 4) & 3u;
    unsigned tile = gid & 15u;
    unsigned wc0  = tile * 32u;
    unsigned t0   = q * 25u;
    unsigned p0   = t0 >> 5;                     // first bit-plane (0,0,1,2)
    unsigned p1   = (t0 + 24u) >> 5;             // second bit-plane (0,1,2,3)
    unsigned tid  = threadIdx.x;

    const uint32_t* sbase = spk + ((size_t)slab << 17);
#pragma unroll
    for (int it = 0; it < 8; ++it) {
        unsigned idx = it * 512u + tid;          // [0, 4096)
        unsigned pl  = idx >> 11;                // 0 / 1
        unsigned r   = idx & 2047u;
        unsigned h   = r >> 5, wcl = r & 31u;
        unsigned tw  = pl ? p1 : p0;
        lds[pl * 2112u + h * 33u + wcl] =
            sbase[((size_t)tw << 15) + h * 512u + wc0 + wcl];
    }
    __syncthreads();

    unsigned wcl = tid >> 4;                     // [0, 32)
    unsigned h0  = (tid & 15u) * 4u;             // 0,4,...,60
    uint32_t r0[4], r1[4];
#pragma unroll
    for (int k = 0; k < 4; ++k) {                // 2-way bank aliasing (free)
        r0[k] = lds[(h0 + k) * 33u + wcl];
        r1[k] = lds[2112u + (h0 + k) * 33u + wcl];
    }

    unsigned b = slab >> 1, ch = slab & 1u;
    unsigned rbase = b * TTOT + ch * CHUNK;      // output region index base
    float4* o4 = (float4*)out;

#pragma unroll
    for (int j = 0; j < 25; ++j) {
        unsigned t   = t0 + j;
        unsigned sel = (t >> 5) != p0;           // wave-uniform
        unsigned bit = t & 31u;
        uint32_t a0 = sel ? r1[0] : r0[0];
        uint32_t a1 = sel ? r1[1] : r0[1];
        uint32_t a2 = sel ? r1[2] : r0[2];
        uint32_t a3 = sel ? r1[3] : r0[3];
        float4 v;
        v.x = (float)((a0 >> bit) & 1u);
        v.y = (float)((a1 >> bit) & 1u);
        v.z = (float)((a2 >> bit) & 1u);
        v.w = (float)((a3 >> bit) & 1u);
        o4[(size_t)(rbase + t) * 8192u + wc0 * 16u + tid] = v;
    }
}

// ---------------- Fallback (ws too small): in-place scheme -----------------
__global__ __launch_bounds__(256) void spike_kernel_ip(const float* __restrict__ x,
                                                       uint8_t* __restrict__ spk) {
    unsigned g     = blockIdx.x * 256u + threadIdx.x;
    unsigned chunk = g >> 16;
    unsigned p     = g & 65535u;
    unsigned b     = p >> 14;
    unsigned i     = (p & 16383u) * 2u;
    unsigned t0    = b * TTOT + chunk * CHUNK;
    const float2* xp = (const float2*)(x + (size_t)t0 * HWC + i);
    uint8_t*      sp = spk + (size_t)t0 * 131072u + i;
    float a0 = 0.0f, a1 = 0.0f;
    for (int tb = 0; tb < CHUNK; tb += 4) {
        float2 v[4];
#pragma unroll
        for (int k = 0; k < 4; ++k) v[k] = xp[(size_t)k * (HWC / 2)];
        xp += 4 * (HWC / 2);
#pragma unroll
        for (int k = 0; k < 4; ++k) {
            a0 += v[k].x; a1 += v[k].y;
            unsigned s0 = 0u, s1 = 0u;
            if (a0 > 2.0f) { s0 = 1u; a0 = 0.0f; }
            if (a1 > 2.0f) { s1 = 1u; a1 = 0.0f; }
            *(uint16_t*)sp = (uint16_t)(s0 | (s1 << 8));
            sp += 131072u;
        }
    }
}

__global__ __launch_bounds__(512) void transpose_ip(float* __restrict__ out) {
    __shared__ uint32_t lds[64 * 129];
    unsigned region = blockIdx.x;
    unsigned tid = threadIdx.x;
    const uint32_t* in32 = (const uint32_t*)((const uint8_t*)out + (size_t)region * 131072u);
#pragma unroll
    for (int it = 0; it < 16; ++it) {
        unsigned idx = it * 512u + tid;
        unsigned h = idx >> 7, wq = idx & 127u;
        lds[h * 129u + wq] = in32[idx];
    }
    __syncthreads();
    float4* out4 = (float4*)out + (size_t)region * 8192u;
#pragma unroll
    for (int it = 0; it < 16; ++it) {
        unsigned f  = it * 512u + tid;
        unsigned wc = f >> 4;
        unsigned h0 = (f & 15u) << 2;
        unsigned wq = wc >> 2, sel = (wc & 3u) * 8u;
        float4 v;
        v.x = (float)((lds[(h0 + 0u) * 129u + wq] >> sel) & 1u);
        v.y = (float)((lds[(h0 + 1u) * 129u + wq] >> sel) & 1u);
        v.z = (float)((lds[(h0 + 2u) * 129u + wq] >> sel) & 1u);
        v.w = (float)((lds[(h0 + 3u) * 129u + wq] >> sel) & 1u);
        out4[f] = v;
    }
}

extern "C" void kernel_launch(void* const* d_in, const int* in_sizes, int n_in,
                              void* d_out, int out_size, void* d_ws, size_t ws_size,
                              hipStream_t stream) {
    (void)in_sizes; (void)n_in; (void)out_size;
    const float* x = (const float*)d_in[0];
    float* out = (float*)d_out;

    const size_t bit_bytes = (size_t)NSLAB * 4u * HWC * 4u;   // 4 MB
    if (ws_size >= bit_bytes) {
        uint32_t* spk = (uint32_t*)d_ws;
        hipLaunchKernelGGL(warm_l3, dim3(2048), dim3(256), 0, stream,
                           (const float4*)x);
        hipLaunchKernelGGL(spike_bits4, dim3(256), dim3(256), 0, stream, x, spk);
        hipLaunchKernelGGL(expand_bits, dim3(512), dim3(512), 0, stream, spk, out);
    } else {
        hipLaunchKernelGGL(spike_kernel_ip, dim3(512), dim3(256), 0, stream, x, (uint8_t*)out);
        hipLaunchKernelGGL(transpose_ip, dim3(NSLAB * CHUNK), dim3(512), 0, stream, out);
    }
}

// Round 9
// 181.624 us; speedup vs baseline: 1.0763x; 1.0712x over previous
//
#include <hip/hip_runtime.h>
#include <stdint.h>

// Input  x[b,t,h,w,c] : (4, 200, 64, 64, 8) fp32   (105 MB)
// Output out[b,t,w,c,h]: (4, 200, 64, 8, 64) fp32  (105 MB)
// Per neuron, per 100-step chunk: acc += x[t]; if (acc > 2) { spike=1; acc=0; }
//
// Round-3 pipeline + slab<->XCD swizzle in K1:
//   slab = bid & 7  (round-robin dispatch => slab k lives on XCD k)
//   Each XCD's 32 blocks cover ONE contiguous 12.8 MB slab; its L2/fabric
//   sees a single near-sequential stream instead of 8 interleaved 128KB-
//   strided streams. Attacks the measured 2.6 TB/s read wall, which L3-warm
//   (round 8) proved lives in the CU->MALL path, not DRAM.
#define HWC    32768
#define NSLAB  8
#define TTOT   200
#define CHUNK  100

// ---------------- K1: bit-packed integrate-and-fire scan (float4) ----------
__global__ __launch_bounds__(256) void spike_bits4(const float* __restrict__ x,
                                                   uint32_t* __restrict__ spk) {
    unsigned bid  = blockIdx.x;                        // [0, 256)
    unsigned slab = bid & 7u;                          // XCD id under %8 rr
    unsigned n0   = ((bid >> 3) * 256u + threadIdx.x) * 4u;  // 4 consecutive
    unsigned b    = slab >> 1, ch = slab & 1u;
    const float4* xp = (const float4*)(x + (size_t)(b * TTOT + ch * CHUNK) * HWC + n0);

    float a0 = 0.0f, a1 = 0.0f, a2 = 0.0f, a3 = 0.0f;
    uint32_t w[4][4] = {{0u,0u,0u,0u},{0u,0u,0u,0u},{0u,0u,0u,0u},{0u,0u,0u,0u}};
    float4 A[4], B[4];

#define LOAD4(V, TBASE)                                                     \
    do {                                                                    \
        _Pragma("unroll")                                                   \
        for (int k = 0; k < 4; ++k)                                         \
            V[k] = xp[(size_t)((TBASE) + k) * (HWC / 4)];                   \
    } while (0)

#define CONS4(V, TBASE)                                                     \
    do {                                                                    \
        _Pragma("unroll")                                                   \
        for (int k = 0; k < 4; ++k) {                                       \
            const int tw = (TBASE) >> 5, bb = ((TBASE) & 31) + k;           \
            a0 += V[k].x; if (a0 > 2.0f) { w[tw][0] |= (1u << bb); a0 = 0.0f; } \
            a1 += V[k].y; if (a1 > 2.0f) { w[tw][1] |= (1u << bb); a1 = 0.0f; } \
            a2 += V[k].z; if (a2 > 2.0f) { w[tw][2] |= (1u << bb); a2 = 0.0f; } \
            a3 += V[k].w; if (a3 > 2.0f) { w[tw][3] |= (1u << bb); a3 = 0.0f; } \
        }                                                                   \
    } while (0)

    LOAD4(A, 0);  LOAD4(B, 4);
    CONS4(A, 0);  LOAD4(A, 8);
    CONS4(B, 4);  LOAD4(B, 12);
    CONS4(A, 8);  LOAD4(A, 16);
    CONS4(B, 12); LOAD4(B, 20);
    CONS4(A, 16); LOAD4(A, 24);
    CONS4(B, 20); LOAD4(B, 28);
    CONS4(A, 24); LOAD4(A, 32);
    CONS4(B, 28); LOAD4(B, 36);
    CONS4(A, 32); LOAD4(A, 40);
    CONS4(B, 36); LOAD4(B, 44);
    CONS4(A, 40); LOAD4(A, 48);
    CONS4(B, 44); LOAD4(B, 52);
    CONS4(A, 48); LOAD4(A, 56);
    CONS4(B, 52); LOAD4(B, 60);
    CONS4(A, 56); LOAD4(A, 64);
    CONS4(B, 60); LOAD4(B, 68);
    CONS4(A, 64); LOAD4(A, 72);
    CONS4(B, 68); LOAD4(B, 76);
    CONS4(A, 72); LOAD4(A, 80);
    CONS4(B, 76); LOAD4(B, 84);
    CONS4(A, 80); LOAD4(A, 88);
    CONS4(B, 84); LOAD4(B, 92);
    CONS4(A, 88); LOAD4(A, 96);
    CONS4(B, 92);
    CONS4(A, 96);                       // t=96..99 -> word 3, bits 0..3
#undef LOAD4
#undef CONS4

    uint32_t* sp = spk + ((size_t)slab << 17);   // slab stride = 4*HWC u32
#pragma unroll
    for (int tw = 0; tw < 4; ++tw) {
        uint4 o; o.x = w[tw][0]; o.y = w[tw][1]; o.z = w[tw][2]; o.w = w[tw][3];
        *(uint4*)(sp + (size_t)tw * HWC + n0) = o;
    }
}

// ---------------- K2: bit expand + transpose (proven round-0 kernel) -------
__global__ __launch_bounds__(512) void expand_bits(const uint32_t* __restrict__ spk,
                                                   float* __restrict__ out) {
    __shared__ uint32_t lds[2 * 2112];           // 2 planes x 64h x 33 (pad)
    unsigned gid  = blockIdx.x;                  // [0, 512)
    unsigned slab = gid >> 6;
    unsigned q    = (gid >> 4) & 3u;
    unsigned tile = gid & 15u;
    unsigned wc0  = tile * 32u;
    unsigned t0   = q * 25u;
    unsigned p0   = t0 >> 5;                     // first bit-plane (0,0,1,2)
    unsigned p1   = (t0 + 24u) >> 5;             // second bit-plane (0,1,2,3)
    unsigned tid  = threadIdx.x;

    const uint32_t* sbase = spk + ((size_t)slab << 17);
#pragma unroll
    for (int it = 0; it < 8; ++it) {
        unsigned idx = it * 512u + tid;          // [0, 4096)
        unsigned pl  = idx >> 11;                // 0 / 1
        unsigned r   = idx & 2047u;
        unsigned h   = r >> 5, wcl = r & 31u;
        unsigned tw  = pl ? p1 : p0;
        lds[pl * 2112u + h * 33u + wcl] =
            sbase[((size_t)tw << 15) + h * 512u + wc0 + wcl];
    }
    __syncthreads();

    unsigned wcl = tid >> 4;                     // [0, 32)
    unsigned h0  = (tid & 15u) * 4u;             // 0,4,...,60
    uint32_t r0[4], r1[4];
#pragma unroll
    for (int k = 0; k < 4; ++k) {                // 2-way bank aliasing (free)
        r0[k] = lds[(h0 + k) * 33u + wcl];
        r1[k] = lds[2112u + (h0 + k) * 33u + wcl];
    }

    unsigned b = slab >> 1, ch = slab & 1u;
    unsigned rbase = b * TTOT + ch * CHUNK;      // output region index base
    float4* o4 = (float4*)out;

#pragma unroll
    for (int j = 0; j < 25; ++j) {
        unsigned t   = t0 + j;
        unsigned sel = (t >> 5) != p0;           // wave-uniform
        unsigned bit = t & 31u;
        uint32_t a0 = sel ? r1[0] : r0[0];
        uint32_t a1 = sel ? r1[1] : r0[1];
        uint32_t a2 = sel ? r1[2] : r0[2];
        uint32_t a3 = sel ? r1[3] : r0[3];
        float4 v;
        v.x = (float)((a0 >> bit) & 1u);
        v.y = (float)((a1 >> bit) & 1u);
        v.z = (float)((a2 >> bit) & 1u);
        v.w = (float)((a3 >> bit) & 1u);
        o4[(size_t)(rbase + t) * 8192u + wc0 * 16u + tid] = v;
    }
}

// ---------------- Fallback (ws too small): in-place scheme -----------------
__global__ __launch_bounds__(256) void spike_kernel_ip(const float* __restrict__ x,
                                                       uint8_t* __restrict__ spk) {
    unsigned g     = blockIdx.x * 256u + threadIdx.x;
    unsigned chunk = g >> 16;
    unsigned p     = g & 65535u;
    unsigned b     = p >> 14;
    unsigned i     = (p & 16383u) * 2u;
    unsigned t0    = b * TTOT + chunk * CHUNK;
    const float2* xp = (const float2*)(x + (size_t)t0 * HWC + i);
    uint8_t*      sp = spk + (size_t)t0 * 131072u + i;
    float a0 = 0.0f, a1 = 0.0f;
    for (int tb = 0; tb < CHUNK; tb += 4) {
        float2 v[4];
#pragma unroll
        for (int k = 0; k < 4; ++k) v[k] = xp[(size_t)k * (HWC / 2)];
        xp += 4 * (HWC / 2);
#pragma unroll
        for (int k = 0; k < 4; ++k) {
            a0 += v[k].x; a1 += v[k].y;
            unsigned s0 = 0u, s1 = 0u;
            if (a0 > 2.0f) { s0 = 1u; a0 = 0.0f; }
            if (a1 > 2.0f) { s1 = 1u; a1 = 0.0f; }
            *(uint16_t*)sp = (uint16_t)(s0 | (s1 << 8));
            sp += 131072u;
        }
    }
}

__global__ __launch_bounds__(512) void transpose_ip(float* __restrict__ out) {
    __shared__ uint32_t lds[64 * 129];
    unsigned region = blockIdx.x;
    unsigned tid = threadIdx.x;
    const uint32_t* in32 = (const uint32_t*)((const uint8_t*)out + (size_t)region * 131072u);
#pragma unroll
    for (int it = 0; it < 16; ++it) {
        unsigned idx = it * 512u + tid;
        unsigned h = idx >> 7, wq = idx & 127u;
        lds[h * 129u + wq] = in32[idx];
    }
    __syncthreads();
    float4* out4 = (float4*)out + (size_t)region * 8192u;
#pragma unroll
    for (int it = 0; it < 16; ++it) {
        unsigned f  = it * 512u + tid;
        unsigned wc = f >> 4;
        unsigned h0 = (f & 15u) << 2;
        unsigned wq = wc >> 2, sel = (wc & 3u) * 8u;
        float4 v;
        v.x = (float)((lds[(h0 + 0u) * 129u + wq] >> sel) & 1u);
        v.y = (float)((lds[(h0 + 1u) * 129u + wq] >> sel) & 1u);
        v.z = (float)((lds[(h0 + 2u) * 129u + wq] >> sel) & 1u);
        v.w = (float)((lds[(h0 + 3u) * 129u + wq] >> sel) & 1u);
        out4[f] = v;
    }
}

extern "C" void kernel_launch(void* const* d_in, const int* in_sizes, int n_in,
                              void* d_out, int out_size, void* d_ws, size_t ws_size,
                              hipStream_t stream) {
    (void)in_sizes; (void)n_in; (void)out_size;
    const float* x = (const float*)d_in[0];
    float* out = (float*)d_out;

    const size_t bit_bytes = (size_t)NSLAB * 4u * HWC * 4u;   // 4 MB
    if (ws_size >= bit_bytes) {
        uint32_t* spk = (uint32_t*)d_ws;
        hipLaunchKernelGGL(spike_bits4, dim3(256), dim3(256), 0, stream, x, spk);
        hipLaunchKernelGGL(expand_bits, dim3(512), dim3(512), 0, stream, spk, out);
    } else {
        hipLaunchKernelGGL(spike_kernel_ip, dim3(512), dim3(256), 0, stream, x, (uint8_t*)out);
        hipLaunchKernelGGL(transpose_ip, dim3(NSLAB * CHUNK), dim3(512), 0, stream, out);
    }
}